// Round 1
// baseline (737.354 us; speedup 1.0000x reference)
//
#include <hip/hip_runtime.h>
#include <hip/hip_bf16.h>

// x:[B,64] fp32, W:[64,10] fp32 -> out:[B,10] fp32. Memory-bound streaming matmul.
// 8 lanes per row; lane `seg` owns k = seg*8 .. seg*8+7 (32 contiguous bytes of x,
// two float4 loads -> wave reads contiguous 2 KiB). W held in 80 VGPRs per lane.
// 3-step shfl_xor butterfly reduces partials across the 8 lanes; lanes seg<5
// each store one float2 of the 10 outputs (contiguous 40 B per row).

#define BLOCK 256
#define GRID  8192
#define IN_DIM 64
#define OUT_DIM 10

__global__ __launch_bounds__(BLOCK) void neat_dense_kernel(
    const float* __restrict__ X, const float* __restrict__ Wg,
    float* __restrict__ out, int B)
{
    const int tid  = blockIdx.x * BLOCK + threadIdx.x;
    const int seg  = tid & 7;          // which 8-wide k-slice of the row
    int row        = tid >> 3;         // row group id
    const int nGroups = (GRID * BLOCK) >> 3;

    // One-time: load this lane's 8 rows of W (8 k x 10 j = 80 floats) into regs.
    // Row stride is 40 B -> 8-aligned, use float2 loads (5 per W row).
    float w[8][10];
#pragma unroll
    for (int kk = 0; kk < 8; ++kk) {
        const float2* wr = (const float2*)(Wg + (size_t)(seg * 8 + kk) * OUT_DIM);
#pragma unroll
        for (int p = 0; p < 5; ++p) {
            float2 t = wr[p];
            w[kk][2 * p]     = t.x;
            w[kk][2 * p + 1] = t.y;
        }
    }

    const float4* X4 = (const float4*)X;

    // depth-1 software prefetch
    float4 a0, a1;
    if (row < B) {
        a0 = X4[(size_t)row * 16 + seg * 2];
        a1 = X4[(size_t)row * 16 + seg * 2 + 1];
    }

    while (row < B) {
        const int nrow = row + nGroups;
        float4 b0, b1;
        if (nrow < B) {
            b0 = X4[(size_t)nrow * 16 + seg * 2];
            b1 = X4[(size_t)nrow * 16 + seg * 2 + 1];
        }

        const float xv[8] = {a0.x, a0.y, a0.z, a0.w, a1.x, a1.y, a1.z, a1.w};

        float acc[OUT_DIM];
#pragma unroll
        for (int j = 0; j < OUT_DIM; ++j) acc[j] = xv[0] * w[0][j];
#pragma unroll
        for (int kk = 1; kk < 8; ++kk) {
#pragma unroll
            for (int j = 0; j < OUT_DIM; ++j)
                acc[j] = fmaf(xv[kk], w[kk][j], acc[j]);
        }

        // butterfly reduce across the 8 lanes of this row (masks 1,2,4 stay in-group)
#pragma unroll
        for (int m = 1; m < 8; m <<= 1) {
#pragma unroll
            for (int j = 0; j < OUT_DIM; ++j)
                acc[j] += __shfl_xor(acc[j], m, 64);
        }

        // lanes 0..4 store float2 pairs {acc[2s],acc[2s+1]}; out+row*10 is 8 B aligned
        if (seg < 5) {
            float2 v;
            v.x = acc[0]; v.y = acc[1];
            if (seg == 1) { v.x = acc[2]; v.y = acc[3]; }
            if (seg == 2) { v.x = acc[4]; v.y = acc[5]; }
            if (seg == 3) { v.x = acc[6]; v.y = acc[7]; }
            if (seg == 4) { v.x = acc[8]; v.y = acc[9]; }
            *(float2*)(out + (size_t)row * OUT_DIM + seg * 2) = v;
        }

        row = nrow;
        a0 = b0; a1 = b1;
    }
}

extern "C" void kernel_launch(void* const* d_in, const int* in_sizes, int n_in,
                              void* d_out, int out_size, void* d_ws, size_t ws_size,
                              hipStream_t stream) {
    const float* x = (const float*)d_in[0];   // [B, 64]
    const float* W = (const float*)d_in[1];   // [64, 10]
    float* out = (float*)d_out;               // [B, 10]
    const int B = in_sizes[0] / IN_DIM;       // 2097152

    neat_dense_kernel<<<GRID, BLOCK, 0, stream>>>(x, W, out, B);
}

// Round 3
// 715.019 us; speedup vs baseline: 1.0312x; 1.0312x over previous
//
#include <hip/hip_runtime.h>
#include <hip/hip_bf16.h>

// x:[B,64] fp32, W:[64,10] fp32 -> out:[B,10] fp32. Memory-bound streaming matmul.
// 8 lanes per row; lane `seg` owns k = seg*8 .. seg*8+7 (32 contiguous bytes of x).
// Each lane holds its 80-float W slice in VGPRs (contiguous 320 B -> 20 float4 loads).
// Cross-lane reduce via DPP butterfly (VALU-only, no LDS/DS ops):
//   xor1 = quad_perm(0xB1), xor2 = quad_perm(0x4E), xor4 == row_half_mirror(0x141)
//   (valid because quads are uniform after the first two stages).
// __launch_bounds__(256,2): 256-VGPR budget -> NO scratch spill of the W array
// (the R1 kernel spilled ~80 regs -> ~5 GB of scratch traffic -> 737 us).

#define BLOCK 256
#define GRID  8192
#define IN_DIM 64
#define OUT_DIM 10

template <int CTRL>
__device__ __forceinline__ float dpp_add(float x) {
    int moved = __builtin_amdgcn_update_dpp(
        __float_as_int(x), __float_as_int(x), CTRL, 0xF, 0xF, true);
    return x + __int_as_float(moved);
}

__global__ __launch_bounds__(BLOCK, 2) void neat_dense_kernel(
    const float* __restrict__ X, const float* __restrict__ Wg,
    float* __restrict__ out, int B)
{
    const int tid  = blockIdx.x * BLOCK + threadIdx.x;
    const int seg  = tid & 7;          // which 8-wide k-slice of the row
    int row        = tid >> 3;         // row group id
    const int nGroups = (GRID * BLOCK) >> 3;

    // One-time: this lane's W slice = rows seg*8..seg*8+7 = contiguous 320 B.
    float w[80];
    {
        const float4* wbase = (const float4*)(Wg + seg * 80);
#pragma unroll
        for (int p = 0; p < 20; ++p) {
            float4 t = wbase[p];
            w[4 * p + 0] = t.x; w[4 * p + 1] = t.y;
            w[4 * p + 2] = t.z; w[4 * p + 3] = t.w;
        }
    }

    const float4* X4 = (const float4*)X;

    // depth-1 software prefetch
    float4 a0, a1;
    if (row < B) {
        a0 = X4[(size_t)row * 16 + seg * 2];
        a1 = X4[(size_t)row * 16 + seg * 2 + 1];
    }

    while (row < B) {
        const int nrow = row + nGroups;
        float4 b0, b1;
        if (nrow < B) {
            b0 = X4[(size_t)nrow * 16 + seg * 2];
            b1 = X4[(size_t)nrow * 16 + seg * 2 + 1];
        }

        const float xv[8] = {a0.x, a0.y, a0.z, a0.w, a1.x, a1.y, a1.z, a1.w};

        float acc[OUT_DIM];
#pragma unroll
        for (int j = 0; j < OUT_DIM; ++j) acc[j] = xv[0] * w[j];
#pragma unroll
        for (int kk = 1; kk < 8; ++kk) {
#pragma unroll
            for (int j = 0; j < OUT_DIM; ++j)
                acc[j] = fmaf(xv[kk], w[kk * OUT_DIM + j], acc[j]);
        }

        // DPP butterfly across the 8 lanes of this row (VALU only, no DS pipe)
#pragma unroll
        for (int j = 0; j < OUT_DIM; ++j) acc[j] = dpp_add<0xB1>(acc[j]);   // quad_perm xor 1
#pragma unroll
        for (int j = 0; j < OUT_DIM; ++j) acc[j] = dpp_add<0x4E>(acc[j]);   // quad_perm xor 2
#pragma unroll
        for (int j = 0; j < OUT_DIM; ++j) acc[j] = dpp_add<0x141>(acc[j]);  // row_half_mirror == xor 4

        // lanes 0..4 store float2 pairs; out+row*10 is 8 B aligned
        if (seg < 5) {
            float2 v;
            v.x = acc[0]; v.y = acc[1];
            if (seg == 1) { v.x = acc[2]; v.y = acc[3]; }
            if (seg == 2) { v.x = acc[4]; v.y = acc[5]; }
            if (seg == 3) { v.x = acc[6]; v.y = acc[7]; }
            if (seg == 4) { v.x = acc[8]; v.y = acc[9]; }
            *(float2*)(out + (size_t)row * OUT_DIM + seg * 2) = v;
        }

        row = nrow;
        a0 = b0; a1 = b1;
    }
}

extern "C" void kernel_launch(void* const* d_in, const int* in_sizes, int n_in,
                              void* d_out, int out_size, void* d_ws, size_t ws_size,
                              hipStream_t stream) {
    const float* x = (const float*)d_in[0];   // [B, 64]
    const float* W = (const float*)d_in[1];   // [64, 10]
    float* out = (float*)d_out;               // [B, 10]
    const int B = in_sizes[0] / IN_DIM;       // 2097152

    neat_dense_kernel<<<GRID, BLOCK, 0, stream>>>(x, W, out, B);
}

// Round 4
// 709.541 us; speedup vs baseline: 1.0392x; 1.0077x over previous
//
#include <hip/hip_runtime.h>
#include <hip/hip_bf16.h>

// x:[B,64] fp32, W:[64,10] fp32 -> out:[B,10] fp32. Memory-bound streaming matmul.
// 8 lanes per row; lane `seg` owns k = seg*8 .. seg*8+7 (32 contiguous bytes of x).
// Each lane holds its 80-float W slice in VGPRs (contiguous 320 B -> 20 float4 loads).
// Cross-lane reduce via DPP butterfly (VALU-only, no LDS/DS ops).
// R4: persistent grid (768 blocks = 3/CU, ~85 iters/block) + launch_bounds(256,3):
//   - W prologue amortized 8x better; aggregate W L2 traffic 671 MB -> 63 MB
//   - 12 waves/CU, 24 KB loads in flight/CU (vs ~9 KB needed at 900-cyc HBM latency)

#define BLOCK 256
#define GRID  768          // 256 CUs x 3 blocks/CU, fully resident (persistent)
#define IN_DIM 64
#define OUT_DIM 10

template <int CTRL>
__device__ __forceinline__ float dpp_add(float x) {
    int moved = __builtin_amdgcn_update_dpp(
        __float_as_int(x), __float_as_int(x), CTRL, 0xF, 0xF, true);
    return x + __int_as_float(moved);
}

__global__ __launch_bounds__(BLOCK, 3) void neat_dense_kernel(
    const float* __restrict__ X, const float* __restrict__ Wg,
    float* __restrict__ out, int B)
{
    const int tid  = blockIdx.x * BLOCK + threadIdx.x;
    const int seg  = tid & 7;          // which 8-wide k-slice of the row
    int row        = tid >> 3;         // row group id
    const int nGroups = (GRID * BLOCK) >> 3;

    // One-time: this lane's W slice = rows seg*8..seg*8+7 = contiguous 320 B.
    float w[80];
    {
        const float4* wbase = (const float4*)(Wg + seg * 80);
#pragma unroll
        for (int p = 0; p < 20; ++p) {
            float4 t = wbase[p];
            w[4 * p + 0] = t.x; w[4 * p + 1] = t.y;
            w[4 * p + 2] = t.z; w[4 * p + 3] = t.w;
        }
    }

    const float4* X4 = (const float4*)X;

    // depth-1 software prefetch
    float4 a0, a1;
    if (row < B) {
        a0 = X4[(size_t)row * 16 + seg * 2];
        a1 = X4[(size_t)row * 16 + seg * 2 + 1];
    }

    while (row < B) {
        const int nrow = row + nGroups;
        float4 b0, b1;
        if (nrow < B) {
            b0 = X4[(size_t)nrow * 16 + seg * 2];
            b1 = X4[(size_t)nrow * 16 + seg * 2 + 1];
        }

        const float xv[8] = {a0.x, a0.y, a0.z, a0.w, a1.x, a1.y, a1.z, a1.w};

        float acc[OUT_DIM];
#pragma unroll
        for (int j = 0; j < OUT_DIM; ++j) acc[j] = xv[0] * w[j];
#pragma unroll
        for (int kk = 1; kk < 8; ++kk) {
#pragma unroll
            for (int j = 0; j < OUT_DIM; ++j)
                acc[j] = fmaf(xv[kk], w[kk * OUT_DIM + j], acc[j]);
        }

        // DPP butterfly across the 8 lanes of this row (VALU only, no DS pipe)
#pragma unroll
        for (int j = 0; j < OUT_DIM; ++j) acc[j] = dpp_add<0xB1>(acc[j]);   // quad_perm xor 1
#pragma unroll
        for (int j = 0; j < OUT_DIM; ++j) acc[j] = dpp_add<0x4E>(acc[j]);   // quad_perm xor 2
#pragma unroll
        for (int j = 0; j < OUT_DIM; ++j) acc[j] = dpp_add<0x141>(acc[j]);  // row_half_mirror == xor 4

        // lanes 0..4 store float2 pairs; wave writes 8 rows x 40 B = 320 contiguous bytes
        if (seg < 5) {
            float2 v;
            v.x = acc[0]; v.y = acc[1];
            if (seg == 1) { v.x = acc[2]; v.y = acc[3]; }
            if (seg == 2) { v.x = acc[4]; v.y = acc[5]; }
            if (seg == 3) { v.x = acc[6]; v.y = acc[7]; }
            if (seg == 4) { v.x = acc[8]; v.y = acc[9]; }
            *(float2*)(out + (size_t)row * OUT_DIM + seg * 2) = v;
        }

        row = nrow;
        a0 = b0; a1 = b1;
    }
}

extern "C" void kernel_launch(void* const* d_in, const int* in_sizes, int n_in,
                              void* d_out, int out_size, void* d_ws, size_t ws_size,
                              hipStream_t stream) {
    const float* x = (const float*)d_in[0];   // [B, 64]
    const float* W = (const float*)d_in[1];   // [64, 10]
    float* out = (float*)d_out;               // [B, 10]
    const int B = in_sizes[0] / IN_DIM;       // 2097152

    neat_dense_kernel<<<GRID, BLOCK, 0, stream>>>(x, W, out, B);
}